// Round 7
// baseline (143.727 us; speedup 1.0000x reference)
//
#include <hip/hip_runtime.h>
#include <math.h>

// DirectionalContrastiveLoss — N=8, C=192, H=W=112, T=0.1
//
// R7: barrier-free hot loop.
//  - tile 8x16 px per block, NT=128 (2 waves). Each wave owns 96 channels and
//    stages its OWN LDS halo tile (wave-private double buffer) -> no
//    __syncthreads in the 12-chunk loop; waves drift freely.
//  - 2 x-adjacent px per lane: one 3x4 float2 window (12 ds_read_b64) serves
//    both px -> 0.67x LDS reads vs 1px/lane.
//  - slot row stride 19 (odd) -> b64 reads hit the optimal 4 touches/bank.
//  - epilogue: 2 barriers to merge the two channel halves (dots via LDS
//    exchange, per-slot sum-of-squares -> inv-norm plane), then masked
//    softmax on wave0, per-block double partial to d_ws.

namespace {
constexpr int N_ = 8, C_ = 192, H_ = 112, W_ = 112;
constexpr int HW = H_ * W_;
constexpr int TPY = 8, TPX = 16;       // px tile
constexpr int RS = 19;                 // slot row stride (10 rows x 18 cols used)
constexpr int SLOTE = 192;             // allocated slots per group
constexpr int NT = 128;                // 2 waves
constexpr int CW = C_ / 2;             // 96 channels per wave
constexpr int KCH = 8;                 // channels per chunk
constexpr int GRP = KCH / 2;           // 4 float2 groups
constexpr int NCHUNK = CW / KCH;       // 12
constexpr int GX = W_ / TPX, GY = H_ / TPY;   // 7, 14
constexpr int NBLK = GX * GY * N_;     // 784
constexpr float INV_T = 10.0f;
constexpr double TOTAL = (double)N_ * N_ * H_ * W_;  // 802816
}

__device__ __forceinline__ float sel3(int d, float a, float b, float c) {
    float r = (d < 0) ? a : b;
    return (d > 0) ? c : r;
}

__device__ __forceinline__ float px_loss(
    const float l[3][3], int gi, int gj, int n,
    const int* __restrict__ labels, const int* __restrict__ dirs)
{
    const int pix = gi * W_ + gj;
    float denom = 0.f, sumlog = 0.f;
#pragma unroll
    for (int m = 0; m < N_; ++m) {
        int d0 = dirs[((m * 2 + 0) * H_ + gi) * W_ + gj];
        int d1 = dirs[((m * 2 + 1) * H_ + gi) * W_ + gj];
        float r0 = sel3(d1, l[0][0], l[0][1], l[0][2]);
        float r1 = sel3(d1, l[1][0], l[1][1], l[1][2]);
        float r2 = sel3(d1, l[2][0], l[2][1], l[2][2]);
        float lm = sel3(d0, r0, r1, r2);
        int labm = labels[m * HW + pix];
        int labn = labels[n * HW + (gi + d0) * W_ + (gj + d1)];
        bool msk = (labm == labn);
        float e = msk ? __expf(lm) : 0.f;
        denom += e;
        sumlog += msk ? lm : -INFINITY;
    }
    return 8.0f * __logf(denom + 1e-6f) - sumlog;
}

extern "C" __global__ void __launch_bounds__(NT, 2)
dcl_main(const float* __restrict__ feat,
         const int* __restrict__ labels,
         const int* __restrict__ dirs,
         double* __restrict__ partial, int use_partial)
{
    __shared__ float2 tl[2 * 2 * GRP * SLOTE];   // [wave][buf][grp][slot] 24.6 KB
    __shared__ float  ssb[SLOTE];
    __shared__ float2 exch[64 * 9];              // wave1 -> wave0 dot exchange

    const int tid = threadIdx.x, lane = tid & 63, wv = tid >> 6;
    const int gx0 = blockIdx.x * TPX, gy0 = blockIdx.y * TPY, n = blockIdx.z;

    // ---- the 3 staging slots this lane owns -> clamped global offsets
    int g0, g1, g2;
    {
        int s = lane, r = s / RS, c = s - r * RS;
        g0 = min(max(gy0 + r - 1, 0), H_ - 1) * W_ + min(max(gx0 + c - 1, 0), W_ - 1);
        s = lane + 64; r = s / RS; c = s - r * RS;
        g1 = min(max(gy0 + r - 1, 0), H_ - 1) * W_ + min(max(gx0 + c - 1, 0), W_ - 1);
        s = lane + 128; r = s / RS; c = s - r * RS;
        g2 = min(max(gy0 + r - 1, 0), H_ - 1) * W_ + min(max(gx0 + c - 1, 0), W_ - 1);
    }
    const int py = lane >> 3, pxp = lane & 7;    // px-pair coords in tile
    const int wb = py * RS + 2 * pxp;            // top-left of 3x4 window
    const float* __restrict__ plane =
        feat + ((size_t)n * C_ + (size_t)wv * CW) * HW;

#define TLP(buf, g) (tl + (((wv * 2 + (buf)) * GRP + (g)) * SLOTE))

    float sA[9], sB[9];
    #pragma unroll
    for (int k = 0; k < 9; ++k) { sA[k] = 0.f; sB[k] = 0.f; }
    float ss0 = 0.f, ss1 = 0.f, ss2 = 0.f;

    // ---- prologue: chunk 0 -> buffer 0 (wave-private, no barrier)
    {
        float v[24];
        #pragma unroll
        for (int k = 0; k < KCH; ++k) {
            v[k]      = plane[(size_t)k * HW + g0];
            v[8 + k]  = plane[(size_t)k * HW + g1];
            v[16 + k] = plane[(size_t)k * HW + g2];
        }
        #pragma unroll
        for (int g = 0; g < GRP; ++g) {
            TLP(0, g)[lane]       = make_float2(v[2 * g],      v[2 * g + 1]);
            TLP(0, g)[lane + 64]  = make_float2(v[8 + 2 * g],  v[8 + 2 * g + 1]);
            TLP(0, g)[lane + 128] = make_float2(v[16 + 2 * g], v[16 + 2 * g + 1]);
        }
        #pragma unroll
        for (int k = 0; k < KCH; ++k) {
            ss0 = fmaf(v[k], v[k], ss0);
            ss1 = fmaf(v[8 + k], v[8 + k], ss1);
            ss2 = fmaf(v[16 + k], v[16 + k], ss2);
        }
    }

    // ---- chunk loop: no __syncthreads (wave-private LDS double buffer)
    for (int t = 0; t < NCHUNK; ++t) {
        float v[24];
        const bool more = (t + 1 < NCHUNK);
        if (more) {
            const float* p = plane + (size_t)(t + 1) * KCH * HW;
            #pragma unroll
            for (int k = 0; k < KCH; ++k) {
                v[k]      = p[(size_t)k * HW + g0];
                v[8 + k]  = p[(size_t)k * HW + g1];
                v[16 + k] = p[(size_t)k * HW + g2];
            }
        }
        const int buf = t & 1;
        #pragma unroll
        for (int g = 0; g < GRP; ++g) {
            const float2* __restrict__ cp = TLP(buf, g);
            float2 w00 = cp[wb],          w01 = cp[wb + 1],          w02 = cp[wb + 2],          w03 = cp[wb + 3];
            float2 w10 = cp[wb + RS],     w11 = cp[wb + RS + 1],     w12 = cp[wb + RS + 2],     w13 = cp[wb + RS + 3];
            float2 w20 = cp[wb + 2 * RS], w21 = cp[wb + 2 * RS + 1], w22 = cp[wb + 2 * RS + 2], w23 = cp[wb + 2 * RS + 3];
            const float2 fA = w11, fB = w12;
            sA[0] = fmaf(fA.x, w00.x, fmaf(fA.y, w00.y, sA[0]));
            sA[1] = fmaf(fA.x, w01.x, fmaf(fA.y, w01.y, sA[1]));
            sA[2] = fmaf(fA.x, w02.x, fmaf(fA.y, w02.y, sA[2]));
            sA[3] = fmaf(fA.x, w10.x, fmaf(fA.y, w10.y, sA[3]));
            sA[4] = fmaf(fA.x, w11.x, fmaf(fA.y, w11.y, sA[4]));
            sA[5] = fmaf(fA.x, w12.x, fmaf(fA.y, w12.y, sA[5]));
            sA[6] = fmaf(fA.x, w20.x, fmaf(fA.y, w20.y, sA[6]));
            sA[7] = fmaf(fA.x, w21.x, fmaf(fA.y, w21.y, sA[7]));
            sA[8] = fmaf(fA.x, w22.x, fmaf(fA.y, w22.y, sA[8]));
            sB[0] = fmaf(fB.x, w01.x, fmaf(fB.y, w01.y, sB[0]));
            sB[1] = fmaf(fB.x, w02.x, fmaf(fB.y, w02.y, sB[1]));
            sB[2] = fmaf(fB.x, w03.x, fmaf(fB.y, w03.y, sB[2]));
            sB[3] = fmaf(fB.x, w11.x, fmaf(fB.y, w11.y, sB[3]));
            sB[4] = fmaf(fB.x, w12.x, fmaf(fB.y, w12.y, sB[4]));
            sB[5] = fmaf(fB.x, w13.x, fmaf(fB.y, w13.y, sB[5]));
            sB[6] = fmaf(fB.x, w21.x, fmaf(fB.y, w21.y, sB[6]));
            sB[7] = fmaf(fB.x, w22.x, fmaf(fB.y, w22.y, sB[7]));
            sB[8] = fmaf(fB.x, w23.x, fmaf(fB.y, w23.y, sB[8]));
        }
        if (more) {
            const int nb = buf ^ 1;
            #pragma unroll
            for (int g = 0; g < GRP; ++g) {
                TLP(nb, g)[lane]       = make_float2(v[2 * g],      v[2 * g + 1]);
                TLP(nb, g)[lane + 64]  = make_float2(v[8 + 2 * g],  v[8 + 2 * g + 1]);
                TLP(nb, g)[lane + 128] = make_float2(v[16 + 2 * g], v[16 + 2 * g + 1]);
            }
            #pragma unroll
            for (int k = 0; k < KCH; ++k) {
                ss0 = fmaf(v[k], v[k], ss0);
                ss1 = fmaf(v[8 + k], v[8 + k], ss1);
                ss2 = fmaf(v[16 + k], v[16 + k], ss2);
            }
        }
    }

    // ---- epilogue: merge channel halves (2 barriers total)
    if (wv == 1) {
        #pragma unroll
        for (int k = 0; k < 9; ++k) exch[lane * 9 + k] = make_float2(sA[k], sB[k]);
        ssb[lane] = ss0; ssb[lane + 64] = ss1; ssb[lane + 128] = ss2;
    }
    __syncthreads();
    if (wv == 0) {
        ssb[lane]       = 1.0f / fmaxf(sqrtf(ss0 + ssb[lane]), 1e-12f);
        ssb[lane + 64]  = 1.0f / fmaxf(sqrtf(ss1 + ssb[lane + 64]), 1e-12f);
        ssb[lane + 128] = 1.0f / fmaxf(sqrtf(ss2 + ssb[lane + 128]), 1e-12f);
    }
    __syncthreads();

    if (wv == 0) {
        #pragma unroll
        for (int k = 0; k < 9; ++k) {
            float2 e = exch[lane * 9 + k];
            sA[k] += e.x; sB[k] += e.y;
        }
        float iv[3][4];
        #pragma unroll
        for (int r = 0; r < 3; ++r)
            #pragma unroll
            for (int c = 0; c < 4; ++c)
                iv[r][c] = ssb[wb + r * RS + c];
        const float iA = iv[1][1] * INV_T, iB = iv[1][2] * INV_T;
        float lA[3][3], lB[3][3];
        #pragma unroll
        for (int r = 0; r < 3; ++r)
            #pragma unroll
            for (int c = 0; c < 3; ++c) {
                lA[r][c] = sA[r * 3 + c] * iA * iv[r][c];
                lB[r][c] = sB[r * 3 + c] * iB * iv[r][c + 1];
            }
        const int gi = gy0 + py, gj = gx0 + 2 * pxp;
        float lp = px_loss(lA, gi, gj, n, labels, dirs)
                 + px_loss(lB, gi, gj + 1, n, labels, dirs);
        #pragma unroll
        for (int off = 32; off > 0; off >>= 1) lp += __shfl_down(lp, off, 64);
        if (lane == 0) {
            const int bid = (blockIdx.z * gridDim.y + blockIdx.y) * gridDim.x + blockIdx.x;
            if (use_partial) partial[bid] = (double)lp;
            else atomicAdd(partial, (double)lp);
        }
    }
#undef TLP
}

extern "C" __global__ void __launch_bounds__(256)
dcl_final(const double* __restrict__ partial, float* __restrict__ out, int nblk)
{
    const int tid = threadIdx.x;
    double s = 0.0;
    for (int i = tid; i < nblk; i += 256) s += partial[i];
    #pragma unroll
    for (int off = 32; off > 0; off >>= 1) s += __shfl_down(s, off, 64);
    __shared__ double red[4];
    const int lane = tid & 63, wv = tid >> 6;
    if (lane == 0) red[wv] = s;
    __syncthreads();
    if (tid == 0) out[0] = (float)((red[0] + red[1] + red[2] + red[3]) / TOTAL);
}

extern "C" void kernel_launch(void* const* d_in, const int* in_sizes, int n_in,
                              void* d_out, int out_size, void* d_ws, size_t ws_size,
                              hipStream_t stream) {
    const float* feat   = (const float*)d_in[0];
    const int*   labels = (const int*)d_in[1];
    const int*   dirs   = (const int*)d_in[2];
    double* acc = (double*)d_ws;
    float*  out = (float*)d_out;

    const int use_partial = (ws_size >= (size_t)NBLK * sizeof(double)) ? 1 : 0;
    if (!use_partial) hipMemsetAsync(acc, 0, sizeof(double), stream);
    dim3 grid(GX, GY, N_);                // (7, 14, 8) = 784 blocks
    dcl_main<<<grid, NT, 0, stream>>>(feat, labels, dirs, acc, use_partial);
    dcl_final<<<1, 256, 0, stream>>>(acc, out, use_partial ? NBLK : 1);
}

// Round 8
// 130.874 us; speedup vs baseline: 1.0982x; 1.0982x over previous
//
#include <hip/hip_runtime.h>
#include <math.h>

// DirectionalContrastiveLoss — N=8, C=192, H=W=112, T=0.1
//
// R8: single-wave blocks, wide tiles, 2px/lane b128 windows.
//  - tile 2 rows x 56 cols, NT=64 (ONE wave) -> 896 blocks = 3.5 independent
//    waves/CU with zero barrier coupling (__syncthreads in a 1-wave block is
//    just a waitcnt). Cross-wave overlap hides VMEM latency.
//  - 58-float slot rows (232B) -> clean line fetches (R6 measured 80MB ~= the
//    77MB input; R7's 19-float rows fetched 160MB).
//  - 2 x-adjacent px per lane, window read as 6 ds_read_b128 per float2-group
//    (slot row stride 58 even, wb even -> 16B aligned).
//  - KCH=8 channels per chunk, 24 chunks, LDS double buffer.
//  - per-block double partial into d_ws; dcl_final reduces 896 partials.

namespace {
constexpr int N_ = 8, C_ = 192, H_ = 112, W_ = 112;
constexpr int HW = H_ * W_;
constexpr int TH = 2;                  // px rows per block
constexpr int WSX = 56;                // px cols per block
constexpr int TROWS = TH + 2;          // 4
constexpr int RS = WSX + 2;            // 58 (even: keeps b128 alignment)
constexpr int TILE_E = TROWS * RS;     // 232 slots
constexpr int NT = 64;                 // 1 wave
constexpr int NS4 = TILE_E - 3 * NT;   // 40 lanes own a 4th slot
constexpr int NPAIR = TH * (WSX / 2);  // 56 compute lanes (2 px each)
constexpr int KCH = 8;                 // channels per chunk
constexpr int GRP = KCH / 2;           // 4 float2 groups
constexpr int NCHUNK = C_ / KCH;       // 24
constexpr int GX = W_ / WSX, GY = H_ / TH;   // 2, 56
constexpr int NBLK = GX * GY * N_;     // 896
constexpr float INV_T = 10.0f;
constexpr double TOTAL = (double)N_ * N_ * H_ * W_;  // 802816
}

__device__ __forceinline__ float sel3(int d, float a, float b, float c) {
    float r = (d < 0) ? a : b;
    return (d > 0) ? c : r;
}

__device__ __forceinline__ float px_loss(
    const float l[3][3], int gi, int gj, int n,
    const int* __restrict__ labels, const int* __restrict__ dirs)
{
    const int pix = gi * W_ + gj;
    float denom = 0.f, sumlog = 0.f;
#pragma unroll
    for (int m = 0; m < N_; ++m) {
        int d0 = dirs[((m * 2 + 0) * H_ + gi) * W_ + gj];
        int d1 = dirs[((m * 2 + 1) * H_ + gi) * W_ + gj];
        float r0 = sel3(d1, l[0][0], l[0][1], l[0][2]);
        float r1 = sel3(d1, l[1][0], l[1][1], l[1][2]);
        float r2 = sel3(d1, l[2][0], l[2][1], l[2][2]);
        float lm = sel3(d0, r0, r1, r2);
        int labm = labels[m * HW + pix];
        int labn = labels[n * HW + (gi + d0) * W_ + (gj + d1)];
        bool msk = (labm == labn);
        float e = msk ? __expf(lm) : 0.f;
        denom += e;
        sumlog += msk ? lm : -INFINITY;
    }
    return 8.0f * __logf(denom + 1e-6f) - sumlog;
}

extern "C" __global__ void __launch_bounds__(NT, 4)
dcl_main(const float* __restrict__ feat,
         const int* __restrict__ labels,
         const int* __restrict__ dirs,
         double* __restrict__ partial, int use_partial)
{
    alignas(16) __shared__ float2 tl[2 * GRP * TILE_E];   // 14.8 KB
    __shared__ float ssb[TILE_E];

    const int lane = threadIdx.x;
    const int gx0 = blockIdx.x * WSX;
    const int gy0 = blockIdx.y * TH;
    const int n   = blockIdx.z;

    // ---- owned staging slots -> clamped global offsets
    const bool has4 = (lane < NS4);
    int gofs[4];
    #pragma unroll
    for (int sI = 0; sI < 4; ++sI) {
        int s = lane + sI * NT;
        if (s >= TILE_E) s = TILE_E - 1;      // harmless duplicate for lanes w/o slot4
        int r = s / RS, c = s - r * RS;
        gofs[sI] = min(max(gy0 + r - 1, 0), H_ - 1) * W_
                 + min(max(gx0 + c - 1, 0), W_ - 1);
    }

    const bool is_px = (lane < NPAIR);
    const int py  = lane / (WSX / 2);          // 0..1
    const int pxp = lane - py * (WSX / 2);     // 0..27
    const int wb  = py * RS + 2 * pxp;         // even -> 16B aligned

    const float* __restrict__ plane = feat + (size_t)n * C_ * HW;

#define TLP(buf, g) (tl + ((buf) * GRP + (g)) * TILE_E)

    float sA[9], sB[9];
    #pragma unroll
    for (int k = 0; k < 9; ++k) { sA[k] = 0.f; sB[k] = 0.f; }
    float ss[4] = {0.f, 0.f, 0.f, 0.f};

    // ---- prologue: chunk 0 -> buffer 0
    {
        float v[4][KCH];
        #pragma unroll
        for (int k = 0; k < KCH; ++k) {
            v[0][k] = plane[(size_t)k * HW + gofs[0]];
            v[1][k] = plane[(size_t)k * HW + gofs[1]];
            v[2][k] = plane[(size_t)k * HW + gofs[2]];
        }
        if (has4)
            #pragma unroll
            for (int k = 0; k < KCH; ++k) v[3][k] = plane[(size_t)k * HW + gofs[3]];
        #pragma unroll
        for (int g = 0; g < GRP; ++g) {
            TLP(0, g)[lane]            = make_float2(v[0][2*g], v[0][2*g+1]);
            TLP(0, g)[lane + NT]       = make_float2(v[1][2*g], v[1][2*g+1]);
            TLP(0, g)[lane + 2 * NT]   = make_float2(v[2][2*g], v[2][2*g+1]);
        }
        if (has4)
            #pragma unroll
            for (int g = 0; g < GRP; ++g)
                TLP(0, g)[lane + 3 * NT] = make_float2(v[3][2*g], v[3][2*g+1]);
        #pragma unroll
        for (int k = 0; k < KCH; ++k) {
            ss[0] = fmaf(v[0][k], v[0][k], ss[0]);
            ss[1] = fmaf(v[1][k], v[1][k], ss[1]);
            ss[2] = fmaf(v[2][k], v[2][k], ss[2]);
            if (has4) ss[3] = fmaf(v[3][k], v[3][k], ss[3]);
        }
    }
    __syncthreads();

    // ---- chunk loop (single wave: "barrier" is just a waitcnt)
    for (int t = 0; t < NCHUNK; ++t) {
        float v[4][KCH];
        const bool more = (t + 1 < NCHUNK);
        if (more) {
            const float* p = plane + (size_t)(t + 1) * KCH * HW;
            #pragma unroll
            for (int k = 0; k < KCH; ++k) {
                v[0][k] = p[(size_t)k * HW + gofs[0]];
                v[1][k] = p[(size_t)k * HW + gofs[1]];
                v[2][k] = p[(size_t)k * HW + gofs[2]];
            }
            if (has4)
                #pragma unroll
                for (int k = 0; k < KCH; ++k) v[3][k] = p[(size_t)k * HW + gofs[3]];
        }

        const int buf = t & 1;
        if (is_px) {
            #pragma unroll
            for (int g = 0; g < GRP; ++g) {
                const float2* __restrict__ cp = TLP(buf, g);
                float4 L0 = *reinterpret_cast<const float4*>(cp + wb);
                float4 R0 = *reinterpret_cast<const float4*>(cp + wb + 2);
                float4 L1 = *reinterpret_cast<const float4*>(cp + wb + RS);
                float4 R1 = *reinterpret_cast<const float4*>(cp + wb + RS + 2);
                float4 L2 = *reinterpret_cast<const float4*>(cp + wb + 2 * RS);
                float4 R2 = *reinterpret_cast<const float4*>(cp + wb + 2 * RS + 2);
                const float fAx = L1.z, fAy = L1.w;     // center px A (row1,col1)
                const float fBx = R1.x, fBy = R1.y;     // center px B (row1,col2)
                sA[0] = fmaf(fAx, L0.x, fmaf(fAy, L0.y, sA[0]));
                sA[1] = fmaf(fAx, L0.z, fmaf(fAy, L0.w, sA[1]));
                sA[2] = fmaf(fAx, R0.x, fmaf(fAy, R0.y, sA[2]));
                sA[3] = fmaf(fAx, L1.x, fmaf(fAy, L1.y, sA[3]));
                sA[4] = fmaf(fAx, L1.z, fmaf(fAy, L1.w, sA[4]));
                sA[5] = fmaf(fAx, R1.x, fmaf(fAy, R1.y, sA[5]));
                sA[6] = fmaf(fAx, L2.x, fmaf(fAy, L2.y, sA[6]));
                sA[7] = fmaf(fAx, L2.z, fmaf(fAy, L2.w, sA[7]));
                sA[8] = fmaf(fAx, R2.x, fmaf(fAy, R2.y, sA[8]));
                sB[0] = fmaf(fBx, L0.z, fmaf(fBy, L0.w, sB[0]));
                sB[1] = fmaf(fBx, R0.x, fmaf(fBy, R0.y, sB[1]));
                sB[2] = fmaf(fBx, R0.z, fmaf(fBy, R0.w, sB[2]));
                sB[3] = fmaf(fBx, L1.z, fmaf(fBy, L1.w, sB[3]));
                sB[4] = fmaf(fBx, R1.x, fmaf(fBy, R1.y, sB[4]));
                sB[5] = fmaf(fBx, R1.z, fmaf(fBy, R1.w, sB[5]));
                sB[6] = fmaf(fBx, L2.z, fmaf(fBy, L2.w, sB[6]));
                sB[7] = fmaf(fBx, R2.x, fmaf(fBy, R2.y, sB[7]));
                sB[8] = fmaf(fBx, R2.z, fmaf(fBy, R2.w, sB[8]));
            }
        }

        if (more) {
            const int nb = buf ^ 1;
            #pragma unroll
            for (int g = 0; g < GRP; ++g) {
                TLP(nb, g)[lane]          = make_float2(v[0][2*g], v[0][2*g+1]);
                TLP(nb, g)[lane + NT]     = make_float2(v[1][2*g], v[1][2*g+1]);
                TLP(nb, g)[lane + 2 * NT] = make_float2(v[2][2*g], v[2][2*g+1]);
            }
            if (has4)
                #pragma unroll
                for (int g = 0; g < GRP; ++g)
                    TLP(nb, g)[lane + 3 * NT] = make_float2(v[3][2*g], v[3][2*g+1]);
            #pragma unroll
            for (int k = 0; k < KCH; ++k) {
                ss[0] = fmaf(v[0][k], v[0][k], ss[0]);
                ss[1] = fmaf(v[1][k], v[1][k], ss[1]);
                ss[2] = fmaf(v[2][k], v[2][k], ss[2]);
                if (has4) ss[3] = fmaf(v[3][k], v[3][k], ss[3]);
            }
        }
        __syncthreads();
    }

    // ---- inv-norm plane
    ssb[lane]          = 1.0f / fmaxf(sqrtf(ss[0]), 1e-12f);
    ssb[lane + NT]     = 1.0f / fmaxf(sqrtf(ss[1]), 1e-12f);
    ssb[lane + 2 * NT] = 1.0f / fmaxf(sqrtf(ss[2]), 1e-12f);
    if (has4) ssb[lane + 3 * NT] = 1.0f / fmaxf(sqrtf(ss[3]), 1e-12f);
    __syncthreads();

    // ---- epilogue
    float lp = 0.0f;
    if (is_px) {
        float iv[3][4];
        #pragma unroll
        for (int r = 0; r < 3; ++r)
            #pragma unroll
            for (int c = 0; c < 4; ++c)
                iv[r][c] = ssb[wb + r * RS + c];
        const float iA = iv[1][1] * INV_T, iB = iv[1][2] * INV_T;
        float lA[3][3], lB[3][3];
        #pragma unroll
        for (int r = 0; r < 3; ++r)
            #pragma unroll
            for (int c = 0; c < 3; ++c) {
                lA[r][c] = sA[r * 3 + c] * iA * iv[r][c];
                lB[r][c] = sB[r * 3 + c] * iB * iv[r][c + 1];
            }
        const int gi = gy0 + py, gj = gx0 + 2 * pxp;
        lp = px_loss(lA, gi, gj, n, labels, dirs)
           + px_loss(lB, gi, gj + 1, n, labels, dirs);
    }
    #pragma unroll
    for (int off = 32; off > 0; off >>= 1) lp += __shfl_down(lp, off, 64);
    if (lane == 0) {
        const int bid = (blockIdx.z * gridDim.y + blockIdx.y) * gridDim.x + blockIdx.x;
        if (use_partial) partial[bid] = (double)lp;
        else atomicAdd(partial, (double)lp);
    }
#undef TLP
}

extern "C" __global__ void __launch_bounds__(256)
dcl_final(const double* __restrict__ partial, float* __restrict__ out, int nblk)
{
    const int tid = threadIdx.x;
    double s = 0.0;
    for (int i = tid; i < nblk; i += 256) s += partial[i];
    #pragma unroll
    for (int off = 32; off > 0; off >>= 1) s += __shfl_down(s, off, 64);
    __shared__ double red[4];
    const int lane = tid & 63, wv = tid >> 6;
    if (lane == 0) red[wv] = s;
    __syncthreads();
    if (tid == 0) out[0] = (float)((red[0] + red[1] + red[2] + red[3]) / TOTAL);
}

extern "C" void kernel_launch(void* const* d_in, const int* in_sizes, int n_in,
                              void* d_out, int out_size, void* d_ws, size_t ws_size,
                              hipStream_t stream) {
    const float* feat   = (const float*)d_in[0];
    const int*   labels = (const int*)d_in[1];
    const int*   dirs   = (const int*)d_in[2];
    double* acc = (double*)d_ws;
    float*  out = (float*)d_out;

    const int use_partial = (ws_size >= (size_t)NBLK * sizeof(double)) ? 1 : 0;
    if (!use_partial) hipMemsetAsync(acc, 0, sizeof(double), stream);
    dim3 grid(GX, GY, N_);                // (2, 56, 8) = 896 blocks
    dcl_main<<<grid, NT, 0, stream>>>(feat, labels, dirs, acc, use_partial);
    dcl_final<<<1, 256, 0, stream>>>(acc, out, use_partial ? NBLK : 1);
}